// Round 1
// baseline (188.345 us; speedup 1.0000x reference)
//
#include <hip/hip_runtime.h>

// Problem constants: B=4, S=512, H=256
#define Bn 4
#define Sn 512
#define Hn 256

// 2*log2(e): pre-scale projections so tanh needs only exp2(x) directly.
#define CC   2.8853900817779268f
#define L2E  1.4426950408889634f

// ---------------------------------------------------------------------------
// Kernel A: gt = (h @ W_t + b_h) * CC        (row-major [row][k])
//           gpT = (h @ W_t') * CC transposed  ([b][k][s])
//           wa2[k] = -2*W_a[k],  cst = -L2E*(sum(W_a) + b_a)
// Grid 256 blocks x 512 threads; each block does 8 rows, thread g-group of 4.
// ---------------------------------------------------------------------------
__global__ __launch_bounds__(512) void proj_kernel(
    const float* __restrict__ hsrc, const float* __restrict__ Wt,
    const float* __restrict__ Wp,   const float* __restrict__ bh,
    const float* __restrict__ Wa,   const float* __restrict__ ba,
    float* __restrict__ gt, float* __restrict__ gpT,
    float* __restrict__ wa2, float* __restrict__ cst)
{
    __shared__ float hs[8 * Hn];       // 8 rows of h
    __shared__ float red4[4];

    const int tid  = threadIdx.x;
    const int row0 = blockIdx.x * 8;

    for (int i = tid; i < 8 * Hn; i += 512)
        hs[i] = hsrc[row0 * Hn + i];
    __syncthreads();

    const int k  = tid & 255;
    const int g  = tid >> 8;           // 0 or 1: which 4-row group
    const int r0 = g * 4;

    float accT[4], accP[4];
    const float bhv = bh[k];
#pragma unroll
    for (int r = 0; r < 4; r++) { accT[r] = bhv; accP[r] = 0.0f; }

    for (int hh = 0; hh < Hn; hh += 4) {
        float wt[4], wp[4];
#pragma unroll
        for (int j = 0; j < 4; j++) {
            wt[j] = Wt[(hh + j) * Hn + k];
            wp[j] = Wp[(hh + j) * Hn + k];
        }
#pragma unroll
        for (int r = 0; r < 4; r++) {
            const float4 hv = *(const float4*)&hs[(r0 + r) * Hn + hh];
            accT[r] = fmaf(hv.x, wt[0], accT[r]);
            accT[r] = fmaf(hv.y, wt[1], accT[r]);
            accT[r] = fmaf(hv.z, wt[2], accT[r]);
            accT[r] = fmaf(hv.w, wt[3], accT[r]);
            accP[r] = fmaf(hv.x, wp[0], accP[r]);
            accP[r] = fmaf(hv.y, wp[1], accP[r]);
            accP[r] = fmaf(hv.z, wp[2], accP[r]);
            accP[r] = fmaf(hv.w, wp[3], accP[r]);
        }
    }

    const int row_base = row0 + r0;
#pragma unroll
    for (int r = 0; r < 4; r++)
        gt[(row_base + r) * Hn + k] = accT[r] * CC;

    const int b  = row_base >> 9;       // /512
    const int s0 = row_base & 511;
    float4 pv;
    pv.x = accP[0] * CC; pv.y = accP[1] * CC;
    pv.z = accP[2] * CC; pv.w = accP[3] * CC;
    *(float4*)&gpT[b * (Hn * Sn) + k * Sn + s0] = pv;  // 16B scattered store

    // --- W_a preprocessing (all blocks reduce; only block 0 stores) ---
    __syncthreads();
    float w = (tid < 256) ? Wa[tid] : 0.0f;
#pragma unroll
    for (int off = 32; off >= 1; off >>= 1)
        w += __shfl_xor(w, off, 64);
    if (tid < 256 && (tid & 63) == 0) red4[tid >> 6] = w;
    __syncthreads();
    if (blockIdx.x == 0) {
        if (tid < 256) wa2[tid] = -2.0f * Wa[tid];
        if (tid == 0)
            cst[0] = -L2E * ((red4[0] + red4[1] + red4[2] + red4[3]) + ba[0]);
    }
}

// ---------------------------------------------------------------------------
// Kernel B: fused scores (tanh via exp2+rcp) + sigmoid + softmax + attn@h.
// Grid = B * (S/4) = 512 blocks x 512 threads; thread = t' column.
// ---------------------------------------------------------------------------
__global__ __launch_bounds__(512) void attn_kernel(
    const float* __restrict__ hsrc, const float* __restrict__ gt,
    const float* __restrict__ gpT,  const float* __restrict__ wa2,
    const float* __restrict__ cst,
    float* __restrict__ out, float* __restrict__ out_attn)
{
    __shared__ float attn_l[4][Sn];   // 8 KB
    __shared__ float part[4][Hn];     // 4 KB
    __shared__ float red[4][8];

    const int tid = threadIdx.x;
    const int b   = blockIdx.x >> 7;
    const int t0  = (blockIdx.x & 127) << 2;

    const float* __restrict__ gtrow = &gt[(b * Sn + t0) * Hn]; // block-uniform
    const float* __restrict__ gpb   = &gpT[b * (Hn * Sn)];
    const int tp = tid;

    float acc[4] = {0.0f, 0.0f, 0.0f, 0.0f};

    for (int hh = 0; hh < Hn; hh += 4) {
#pragma unroll
        for (int j = 0; j < 4; j++) {
            const float v  = gpb[(hh + j) * Sn + tp];  // coalesced
            const float w2 = wa2[hh + j];              // uniform -> s_load
#pragma unroll
            for (int r = 0; r < 4; r++) {
                const float x = gtrow[r * Hn + hh + j] + v; // both pre-scaled by CC
                const float e = __builtin_amdgcn_exp2f(x);  // e^{2z}
                const float rc = __builtin_amdgcn_rcpf(e + 1.0f);
                acc[r] = fmaf(w2, rc, acc[r]);              // sum of -2*wa/(1+e^{2z})
            }
        }
    }

    // score s = S_wa + acc + b_a ;  sig = 1/(1+e^{-s}) ; ex = e^{sig}
    const float k0 = cst[0];  // = -L2E*(S_wa + b_a)
    float ex[4];
#pragma unroll
    for (int r = 0; r < 4; r++) {
        const float e1  = __builtin_amdgcn_exp2f(fmaf(-L2E, acc[r], k0));
        const float sig = __builtin_amdgcn_rcpf(1.0f + e1);
        ex[r] = __builtin_amdgcn_exp2f(L2E * sig);  // sig in (0,1): no max-sub needed
    }

    // softmax denominator: block-wide sum over 512 threads, per r
    const int lane = tid & 63, wid = tid >> 6;
#pragma unroll
    for (int r = 0; r < 4; r++) {
        float v = ex[r];
#pragma unroll
        for (int off = 32; off >= 1; off >>= 1)
            v += __shfl_xor(v, off, 64);
        if (lane == 0) red[r][wid] = v;
    }
    __syncthreads();

#pragma unroll
    for (int r = 0; r < 4; r++) {
        const float tot = red[r][0] + red[r][1] + red[r][2] + red[r][3] +
                          red[r][4] + red[r][5] + red[r][6] + red[r][7];
        const float a = ex[r] * __builtin_amdgcn_rcpf(tot);
        attn_l[r][tp] = a;
        out_attn[(b * Sn + t0 + r) * Sn + tp] = a;  // coalesced
    }
    __syncthreads();

    // output[b, t0+r, hcol] = sum_tp attn[r][tp] * h[b, tp, hcol]
    const int hcol = tid & 255;
    const int half = tid >> 8;
    const float* __restrict__ hb = &hsrc[(b * Sn + half * 256) * Hn];
    float oacc[4] = {0.0f, 0.0f, 0.0f, 0.0f};
#pragma unroll 4
    for (int j = 0; j < 256; j++) {
        const float hv = hb[j * Hn + hcol];         // coalesced
        const int tpj = half * 256 + j;
#pragma unroll
        for (int r = 0; r < 4; r++)
            oacc[r] = fmaf(attn_l[r][tpj], hv, oacc[r]);  // LDS broadcast
    }
    if (half == 1) {
#pragma unroll
        for (int r = 0; r < 4; r++) part[r][hcol] = oacc[r];
    }
    __syncthreads();
    if (half == 0) {
#pragma unroll
        for (int r = 0; r < 4; r++)
            out[(b * Sn + t0 + r) * Hn + hcol] = oacc[r] + part[r][hcol];
    }
}

extern "C" void kernel_launch(void* const* d_in, const int* in_sizes, int n_in,
                              void* d_out, int out_size, void* d_ws, size_t ws_size,
                              hipStream_t stream) {
    const float* h   = (const float*)d_in[0];
    const float* Wt  = (const float*)d_in[1];
    const float* Wtp = (const float*)d_in[2];
    const float* bh  = (const float*)d_in[3];
    const float* Wa  = (const float*)d_in[4];
    const float* ba  = (const float*)d_in[5];

    float* out      = (float*)d_out;                 // (B,S,H) = 524288
    float* out_attn = out + Bn * Sn * Hn;            // (B,S,S) = 1048576

    float* ws  = (float*)d_ws;
    float* gt  = ws;                                  // 524288 floats
    float* gpT = ws + Bn * Sn * Hn;                   // 524288 floats
    float* wa2 = ws + 2 * Bn * Sn * Hn;               // 256 floats
    float* cst = wa2 + 256;                           // 1 float

    proj_kernel<<<dim3(2048 / 8), dim3(512), 0, stream>>>(
        h, Wt, Wtp, bh, Wa, ba, gt, gpT, wa2, cst);

    attn_kernel<<<dim3(Bn * (Sn / 4)), dim3(512), 0, stream>>>(
        h, gt, gpT, wa2, cst, out, out_attn);
}

// Round 2
// 164.153 us; speedup vs baseline: 1.1474x; 1.1474x over previous
//
#include <hip/hip_runtime.h>

// Problem constants: B=4, S=512, H=256
#define Bn 4
#define Sn 512
#define Hn 256

// 2*log2(e): pre-scale projections so tanh needs only exp2.
#define CC   2.8853900817779268f
#define L2E  1.4426950408889634f

// ---------------------------------------------------------------------------
// Kernel A: Egt[row][k]        = exp2( (h@W_t + b_h) * CC )      row-major
//           Egp4[b][k/4][s][j] = exp2( (h@W_t')      * CC )      k-interleaved
//           wa2[k] = -2*W_a[k],  cst = -L2E*(sum(W_a) + b_a)
// Grid 256 blocks x 512 threads; each block does 8 rows, thread-group of 4.
// ---------------------------------------------------------------------------
__global__ __launch_bounds__(512) void proj_kernel(
    const float* __restrict__ hsrc, const float* __restrict__ Wt,
    const float* __restrict__ Wp,   const float* __restrict__ bh,
    const float* __restrict__ Wa,   const float* __restrict__ ba,
    float* __restrict__ Egt, float* __restrict__ Egp4,
    float* __restrict__ wa2, float* __restrict__ cst)
{
    __shared__ float hs[8 * Hn];       // 8 rows of h
    __shared__ float red4[4];

    const int tid  = threadIdx.x;
    const int row0 = blockIdx.x * 8;

    for (int i = tid; i < 8 * Hn; i += 512)
        hs[i] = hsrc[row0 * Hn + i];
    __syncthreads();

    const int k  = tid & 255;
    const int g  = tid >> 8;           // 0 or 1: which 4-row group
    const int r0 = g * 4;

    float accT[4], accP[4];
    const float bhv = bh[k];
#pragma unroll
    for (int r = 0; r < 4; r++) { accT[r] = bhv; accP[r] = 0.0f; }

    for (int hh = 0; hh < Hn; hh += 4) {
        float wt[4], wp[4];
#pragma unroll
        for (int j = 0; j < 4; j++) {
            wt[j] = Wt[(hh + j) * Hn + k];
            wp[j] = Wp[(hh + j) * Hn + k];
        }
#pragma unroll
        for (int r = 0; r < 4; r++) {
            const float4 hv = *(const float4*)&hs[(r0 + r) * Hn + hh];
            accT[r] = fmaf(hv.x, wt[0], accT[r]);
            accT[r] = fmaf(hv.y, wt[1], accT[r]);
            accT[r] = fmaf(hv.z, wt[2], accT[r]);
            accT[r] = fmaf(hv.w, wt[3], accT[r]);
            accP[r] = fmaf(hv.x, wp[0], accP[r]);
            accP[r] = fmaf(hv.y, wp[1], accP[r]);
            accP[r] = fmaf(hv.z, wp[2], accP[r]);
            accP[r] = fmaf(hv.w, wp[3], accP[r]);
        }
    }

    const int row_base = row0 + r0;
#pragma unroll
    for (int r = 0; r < 4; r++)
        Egt[(row_base + r) * Hn + k] = __builtin_amdgcn_exp2f(accT[r] * CC);

    const int b  = row_base >> 9;       // /512
    const int s0 = row_base & 511;
#pragma unroll
    for (int r = 0; r < 4; r++)
        Egp4[b * (Hn * Sn) + ((k >> 2) * Sn + (s0 + r)) * 4 + (k & 3)] =
            __builtin_amdgcn_exp2f(accP[r] * CC);

    // --- W_a preprocessing (all blocks reduce; only block 0 stores) ---
    __syncthreads();
    float w = (tid < 256) ? Wa[tid] : 0.0f;
#pragma unroll
    for (int off = 32; off >= 1; off >>= 1)
        w += __shfl_xor(w, off, 64);
    if (tid < 256 && (tid & 63) == 0) red4[tid >> 6] = w;
    __syncthreads();
    if (blockIdx.x == 0) {
        if (tid < 256) wa2[tid] = -2.0f * Wa[tid];
        if (tid == 0)
            cst[0] = -L2E * ((red4[0] + red4[1] + red4[2] + red4[3]) + ba[0]);
    }
}

// ---------------------------------------------------------------------------
// Kernel B: fused scores via factorized exp (1 rcp + 2 fma per element),
// then sigmoid + softmax + attn@h.
// Grid = B * (S/4) = 512 blocks x 512 threads; thread = t' column.
// ---------------------------------------------------------------------------
__global__ __launch_bounds__(512) void attn_kernel(
    const float* __restrict__ hsrc, const float* __restrict__ Egt,
    const float* __restrict__ Egp4, const float* __restrict__ wa2,
    const float* __restrict__ cst,
    float* __restrict__ out, float* __restrict__ out_attn)
{
    __shared__ float attn_l[4][Sn];   // 8 KB
    __shared__ float part[4][Hn];     // 4 KB
    __shared__ float red[4][8];

    const int tid = threadIdx.x;
    const int b   = blockIdx.x >> 7;
    const int t0  = (blockIdx.x & 127) << 2;

    const float* __restrict__ egt = &Egt[(b * Sn + t0) * Hn]; // block-uniform
    const float* __restrict__ epb = &Egp4[b * (Hn * Sn)];
    const int tp = tid;

    float acc[4] = {0.0f, 0.0f, 0.0f, 0.0f};

#pragma unroll 2
    for (int k4 = 0; k4 < Hn / 4; k4++) {
        const float4 ep4 = *(const float4*)&epb[(k4 * Sn + tp) * 4];
        const float* epa = (const float*)&ep4;
#pragma unroll
        for (int j = 0; j < 4; j++) {
            const float epj = epa[j];
            const float w2  = wa2[k4 * 4 + j];           // uniform -> s_load
#pragma unroll
            for (int r = 0; r < 4; r++) {
                // d = 1 + exp2(gt)*exp2(gp) ; tanh contribution = w2 * rcp(d)
                const float d = fmaf(epj, egt[r * Hn + k4 * 4 + j], 1.0f);
                acc[r] = fmaf(w2, __builtin_amdgcn_rcpf(d), acc[r]);
            }
        }
    }

    // score s = S_wa + acc + b_a ;  sig = 1/(1+e^{-s}) ; ex = e^{sig}
    const float k0 = cst[0];  // = -L2E*(S_wa + b_a)
    float ex[4];
#pragma unroll
    for (int r = 0; r < 4; r++) {
        const float e1  = __builtin_amdgcn_exp2f(fmaf(-L2E, acc[r], k0));
        const float sig = __builtin_amdgcn_rcpf(1.0f + e1);
        ex[r] = __builtin_amdgcn_exp2f(L2E * sig);  // sig in (0,1): no max-sub needed
    }

    // softmax denominator: block-wide sum over 512 threads, per r
    const int lane = tid & 63, wid = tid >> 6;
#pragma unroll
    for (int r = 0; r < 4; r++) {
        float v = ex[r];
#pragma unroll
        for (int off = 32; off >= 1; off >>= 1)
            v += __shfl_xor(v, off, 64);
        if (lane == 0) red[r][wid] = v;
    }
    __syncthreads();

#pragma unroll
    for (int r = 0; r < 4; r++) {
        const float tot = red[r][0] + red[r][1] + red[r][2] + red[r][3] +
                          red[r][4] + red[r][5] + red[r][6] + red[r][7];
        const float a = ex[r] * __builtin_amdgcn_rcpf(tot);
        attn_l[r][tp] = a;
        out_attn[(b * Sn + t0 + r) * Sn + tp] = a;  // coalesced
    }
    __syncthreads();

    // output[b, t0+r, hcol] = sum_tp attn[r][tp] * h[b, tp, hcol]
    const int hcol = tid & 255;
    const int half = tid >> 8;
    const float* __restrict__ hb = &hsrc[(b * Sn + half * 256) * Hn];
    float oacc[4] = {0.0f, 0.0f, 0.0f, 0.0f};
#pragma unroll 4
    for (int j = 0; j < 256; j++) {
        const float hv = hb[j * Hn + hcol];         // coalesced
        const int tpj = half * 256 + j;
#pragma unroll
        for (int r = 0; r < 4; r++)
            oacc[r] = fmaf(attn_l[r][tpj], hv, oacc[r]);  // LDS broadcast
    }
    if (half == 1) {
#pragma unroll
        for (int r = 0; r < 4; r++) part[r][hcol] = oacc[r];
    }
    __syncthreads();
    if (half == 0) {
#pragma unroll
        for (int r = 0; r < 4; r++)
            out[(b * Sn + t0 + r) * Hn + hcol] = oacc[r] + part[r][hcol];
    }
}

extern "C" void kernel_launch(void* const* d_in, const int* in_sizes, int n_in,
                              void* d_out, int out_size, void* d_ws, size_t ws_size,
                              hipStream_t stream) {
    const float* h   = (const float*)d_in[0];
    const float* Wt  = (const float*)d_in[1];
    const float* Wtp = (const float*)d_in[2];
    const float* bh  = (const float*)d_in[3];
    const float* Wa  = (const float*)d_in[4];
    const float* ba  = (const float*)d_in[5];

    float* out      = (float*)d_out;                 // (B,S,H) = 524288
    float* out_attn = out + Bn * Sn * Hn;            // (B,S,S) = 1048576

    float* ws   = (float*)d_ws;
    float* Egt  = ws;                                 // 524288 floats
    float* Egp4 = ws + Bn * Sn * Hn;                  // 524288 floats
    float* wa2  = ws + 2 * Bn * Sn * Hn;              // 256 floats
    float* cst  = wa2 + 256;                          // 1 float

    proj_kernel<<<dim3(2048 / 8), dim3(512), 0, stream>>>(
        h, Wt, Wtp, bh, Wa, ba, Egt, Egp4, wa2, cst);

    attn_kernel<<<dim3(Bn * (Sn / 4)), dim3(512), 0, stream>>>(
        h, Egt, Egp4, wa2, cst, out, out_attn);
}

// Round 3
// 137.663 us; speedup vs baseline: 1.3682x; 1.1924x over previous
//
#include <hip/hip_runtime.h>

// Problem constants: B=4, S=512, H=256
#define Bn 4
#define Sn 512
#define Hn 256

// 2*log2(e): pre-scale projections so tanh needs only exp2.
#define CC   2.8853900817779268f
#define L2E  1.4426950408889634f

// ---------------------------------------------------------------------------
// Kernel A: Egt[row][k]        = exp2( (h@W_t + b_h) * CC )   row-major
//           Egp4[b][k>>2][s][k&3] = exp2( (h@W_t') * CC )     k-interleaved,
//              written COALESCED via an LDS transpose (R2's scatter was the
//              69us stall: 64 transactions per wave-store).
//           wa2[k] = -2*W_a[k],  cst = -L2E*(sum(W_a) + b_a)
// Grid 256 blocks x 512 threads; block = 8 rows, k = tid&255, g = tid>>8.
// ---------------------------------------------------------------------------
__global__ __launch_bounds__(512) void proj_kernel(
    const float* __restrict__ hsrc, const float* __restrict__ Wt,
    const float* __restrict__ Wp,   const float* __restrict__ bh,
    const float* __restrict__ Wa,   const float* __restrict__ ba,
    float* __restrict__ Egt, float* __restrict__ Egp4,
    float* __restrict__ wa2, float* __restrict__ cst)
{
    __shared__ float hs[8 * Hn];     // 8 KB: 8 rows of h
    __shared__ float eps[Hn * 9];    // 9 KB: transpose buffer [k][row], pad 9
    __shared__ float red4[8];

    const int tid  = threadIdx.x;
    const int row0 = blockIdx.x * 8;

    for (int i = tid; i < 8 * Hn; i += 512)
        hs[i] = hsrc[row0 * Hn + i];
    __syncthreads();

    const int k  = tid & 255;
    const int g  = tid >> 8;           // 0 or 1: which 4-row group
    const int r0 = g * 4;

    float accT[4], accP[4];
    const float bhv = bh[k];
#pragma unroll
    for (int r = 0; r < 4; r++) { accT[r] = bhv; accP[r] = 0.0f; }

    const float* __restrict__ wtp = Wt + k;
    const float* __restrict__ wpp = Wp + k;

#pragma unroll 2
    for (int hh = 0; hh < Hn; hh += 4) {
        float wt[4], wp[4];
#pragma unroll
        for (int j = 0; j < 4; j++) {
            wt[j] = wtp[(hh + j) * Hn];
            wp[j] = wpp[(hh + j) * Hn];
        }
#pragma unroll
        for (int r = 0; r < 4; r++) {
            const float4 hv = *(const float4*)&hs[(r0 + r) * Hn + hh];
            accT[r] = fmaf(hv.x, wt[0], accT[r]);
            accT[r] = fmaf(hv.y, wt[1], accT[r]);
            accT[r] = fmaf(hv.z, wt[2], accT[r]);
            accT[r] = fmaf(hv.w, wt[3], accT[r]);
            accP[r] = fmaf(hv.x, wp[0], accP[r]);
            accP[r] = fmaf(hv.y, wp[1], accP[r]);
            accP[r] = fmaf(hv.z, wp[2], accP[r]);
            accP[r] = fmaf(hv.w, wp[3], accP[r]);
        }
    }

    const int row_base = row0 + r0;
#pragma unroll
    for (int r = 0; r < 4; r++)
        Egt[(row_base + r) * Hn + k] = __builtin_amdgcn_exp2f(accT[r] * CC);

    // Stage P-exponentials in LDS: eps[k][row], stride 9 (9 coprime 32 -> no
    // bank conflicts on the k-strided writes).
#pragma unroll
    for (int r = 0; r < 4; r++)
        eps[k * 9 + r0 + r] = __builtin_amdgcn_exp2f(accP[r] * CC);
    __syncthreads();

    // Coalesced re-emit: thread t writes float4 for chunk c = t>>3, row = t&7.
    // Target addr = b*131072 + c*2048 + (s0+row)*4 + {0..3}; lanes 0..7 cover
    // 128 contiguous bytes -> 8 dense transactions per wave-store.
    {
        const int b   = row0 >> 9;
        const int s0  = row0 & 511;
        const int c   = tid >> 3;       // 0..63: k-group
        const int row = tid & 7;
        float4 v;
        v.x = eps[(c * 4 + 0) * 9 + row];
        v.y = eps[(c * 4 + 1) * 9 + row];
        v.z = eps[(c * 4 + 2) * 9 + row];
        v.w = eps[(c * 4 + 3) * 9 + row];
        *(float4*)&Egp4[b * (Hn * Sn) + c * (4 * Sn) + (s0 + row) * 4] = v;
    }

    // --- W_a preprocessing (block 0 only; block-uniform branch) ---
    if (blockIdx.x == 0) {
        float w = (tid < 256) ? Wa[tid] : 0.0f;
#pragma unroll
        for (int off = 32; off >= 1; off >>= 1)
            w += __shfl_xor(w, off, 64);
        if ((tid & 63) == 0) red4[tid >> 6] = w;
        __syncthreads();
        if (tid < 256) wa2[tid] = -2.0f * Wa[tid];
        if (tid == 0) {
            float s = 0.0f;
            for (int i = 0; i < 8; i++) s += red4[i];
            cst[0] = -L2E * (s + ba[0]);
        }
    }
}

// ---------------------------------------------------------------------------
// Kernel B: scores via factorized exp (1 rcp + 2 fma / element) + sigmoid +
// softmax. Writes attention weights only (output GEMM moved to kernel C).
// One-ahead float4 prefetch hides L2 latency (192cy math per load).
// Grid = B * (S/4) = 512 blocks x 512 threads; thread = t' column.
// ---------------------------------------------------------------------------
__global__ __launch_bounds__(512) void score_kernel(
    const float* __restrict__ Egt,  const float* __restrict__ Egp4,
    const float* __restrict__ wa2,  const float* __restrict__ cst,
    float* __restrict__ out_attn)
{
    __shared__ float red[4][8];

    const int tid = threadIdx.x;
    const int b   = blockIdx.x >> 7;
    const int t0  = (blockIdx.x & 127) << 2;

    const float* __restrict__ egt = Egt + (b * Sn + t0) * Hn;     // uniform
    const float4* __restrict__ ep = (const float4*)(Egp4 + b * (Hn * Sn));
    const int tp = tid;

    float acc0 = 0.f, acc1 = 0.f, acc2 = 0.f, acc3 = 0.f;

    float4 cur = ep[tp];   // k4 = 0
#pragma unroll 2
    for (int k4 = 0; k4 < 64; k4++) {
        const int nk4 = (k4 < 63) ? (k4 + 1) : 63;
        const float4 nxt = ep[nk4 * Sn + tp];   // prefetch while computing
        const float* ca = (const float*)&cur;
#pragma unroll
        for (int j = 0; j < 4; j++) {
            const float epj = ca[j];
            const float w2  = wa2[k4 * 4 + j];                    // s_load
            const float e0  = egt[0 * Hn + k4 * 4 + j];           // s_load
            const float e1  = egt[1 * Hn + k4 * 4 + j];
            const float e2  = egt[2 * Hn + k4 * 4 + j];
            const float e3  = egt[3 * Hn + k4 * 4 + j];
            acc0 = fmaf(w2, __builtin_amdgcn_rcpf(fmaf(epj, e0, 1.0f)), acc0);
            acc1 = fmaf(w2, __builtin_amdgcn_rcpf(fmaf(epj, e1, 1.0f)), acc1);
            acc2 = fmaf(w2, __builtin_amdgcn_rcpf(fmaf(epj, e2, 1.0f)), acc2);
            acc3 = fmaf(w2, __builtin_amdgcn_rcpf(fmaf(epj, e3, 1.0f)), acc3);
        }
        cur = nxt;
    }

    // score s = S_wa + acc + b_a ;  sig = 1/(1+e^{-s}) ; ex = e^{sig}
    const float k0 = cst[0];  // = -L2E*(S_wa + b_a)
    float accs[4] = {acc0, acc1, acc2, acc3};
    float ex[4];
#pragma unroll
    for (int r = 0; r < 4; r++) {
        const float e1  = __builtin_amdgcn_exp2f(fmaf(-L2E, accs[r], k0));
        const float sig = __builtin_amdgcn_rcpf(1.0f + e1);
        ex[r] = __builtin_amdgcn_exp2f(L2E * sig);  // sig in (0,1): no max-sub
    }

    // softmax denominator across 512 threads, per row r
    const int lane = tid & 63, wid = tid >> 6;
#pragma unroll
    for (int r = 0; r < 4; r++) {
        float v = ex[r];
#pragma unroll
        for (int off = 32; off >= 1; off >>= 1)
            v += __shfl_xor(v, off, 64);
        if (lane == 0) red[r][wid] = v;
    }
    __syncthreads();

#pragma unroll
    for (int r = 0; r < 4; r++) {
        const float tot = red[r][0] + red[r][1] + red[r][2] + red[r][3] +
                          red[r][4] + red[r][5] + red[r][6] + red[r][7];
        out_attn[(b * Sn + t0 + r) * Sn + tp] = ex[r] * __builtin_amdgcn_rcpf(tot);
    }
}

// ---------------------------------------------------------------------------
// Kernel C: out[b,t,:] = attn[b,t,:] @ h[b,:,:].
// attn rows are block-uniform -> scalar s_loads (SMEM pipe, no VALU/VMEM
// cost); only h streams through vector loads (coalesced over hcol).
// Grid = 512 blocks x 512 threads; thread = (hcol, tp-half).
// ---------------------------------------------------------------------------
__global__ __launch_bounds__(512) void out_kernel(
    const float* __restrict__ hsrc, const float* __restrict__ attn,
    float* __restrict__ out)
{
    __shared__ float part[4][Hn];    // 4 KB

    const int tid  = threadIdx.x;
    const int b    = blockIdx.x >> 7;
    const int t0   = (blockIdx.x & 127) << 2;
    const int hcol = tid & 255;
    const int half = tid >> 8;
    // force wave-uniform tp base into an SGPR so attn loads scalarize
    const int tp0  = __builtin_amdgcn_readfirstlane(half << 8);

    const float* __restrict__ ar = attn + (b * Sn + t0) * Sn + tp0;
    const float* __restrict__ hb = hsrc + (b * Sn + tp0) * Hn + hcol;

    float a0 = 0.f, a1 = 0.f, a2 = 0.f, a3 = 0.f;
#pragma unroll 2
    for (int j = 0; j < 256; j += 4) {
        float hv[4];
#pragma unroll
        for (int i = 0; i < 4; i++) hv[i] = hb[(j + i) * Hn];   // vector, coalesced
#pragma unroll
        for (int i = 0; i < 4; i++) {
            a0 = fmaf(ar[0 * Sn + j + i], hv[i], a0);           // s_load operands
            a1 = fmaf(ar[1 * Sn + j + i], hv[i], a1);
            a2 = fmaf(ar[2 * Sn + j + i], hv[i], a2);
            a3 = fmaf(ar[3 * Sn + j + i], hv[i], a3);
        }
    }

    if (half == 1) {
        part[0][hcol] = a0; part[1][hcol] = a1;
        part[2][hcol] = a2; part[3][hcol] = a3;
    }
    __syncthreads();
    if (half == 0) {
        out[(b * Sn + t0 + 0) * Hn + hcol] = a0 + part[0][hcol];
        out[(b * Sn + t0 + 1) * Hn + hcol] = a1 + part[1][hcol];
        out[(b * Sn + t0 + 2) * Hn + hcol] = a2 + part[2][hcol];
        out[(b * Sn + t0 + 3) * Hn + hcol] = a3 + part[3][hcol];
    }
}

extern "C" void kernel_launch(void* const* d_in, const int* in_sizes, int n_in,
                              void* d_out, int out_size, void* d_ws, size_t ws_size,
                              hipStream_t stream) {
    const float* h   = (const float*)d_in[0];
    const float* Wt  = (const float*)d_in[1];
    const float* Wtp = (const float*)d_in[2];
    const float* bh  = (const float*)d_in[3];
    const float* Wa  = (const float*)d_in[4];
    const float* ba  = (const float*)d_in[5];

    float* out      = (float*)d_out;                 // (B,S,H) = 524288
    float* out_attn = out + Bn * Sn * Hn;            // (B,S,S) = 1048576

    float* ws   = (float*)d_ws;
    float* Egt  = ws;                                 // 524288 floats
    float* Egp4 = ws + Bn * Sn * Hn;                  // 524288 floats
    float* wa2  = ws + 2 * Bn * Sn * Hn;              // 256 floats
    float* cst  = wa2 + 256;                          // 1 float

    proj_kernel<<<dim3(2048 / 8), dim3(512), 0, stream>>>(
        h, Wt, Wtp, bh, Wa, ba, Egt, Egp4, wa2, cst);

    score_kernel<<<dim3(Bn * (Sn / 4)), dim3(512), 0, stream>>>(
        Egt, Egp4, wa2, cst, out_attn);

    out_kernel<<<dim3(Bn * (Sn / 4)), dim3(512), 0, stream>>>(
        h, out_attn, out);
}

// Round 4
// 136.084 us; speedup vs baseline: 1.3840x; 1.0116x over previous
//
#include <hip/hip_runtime.h>

// Problem constants: B=4, S=512, H=256
#define Bn 4
#define Sn 512
#define Hn 256

// 2*log2(e): pre-scale projections so tanh needs only exp2.
#define CC   2.8853900817779268f
#define L2E  1.4426950408889634f

// ---------------------------------------------------------------------------
// Kernel A: Egt[row][k]           = exp2( (h@W_t + b_h) * CC )   row-major
//           Egp4[b][k>>2][s][k&3] = exp2( (h@W_t') * CC )        k-interleaved,
//              written coalesced via LDS transpose.
//           wa2[k] = -2*W_a[k],  cst = -L2E*(sum(W_a) + b_a)
// Grid 256 blocks x 512 threads; block = 8 rows, k = tid&255, g = tid>>8.
// ---------------------------------------------------------------------------
__global__ __launch_bounds__(512) void proj_kernel(
    const float* __restrict__ hsrc, const float* __restrict__ Wt,
    const float* __restrict__ Wp,   const float* __restrict__ bh,
    const float* __restrict__ Wa,   const float* __restrict__ ba,
    float* __restrict__ Egt, float* __restrict__ Egp4,
    float* __restrict__ wa2, float* __restrict__ cst)
{
    __shared__ float hs[8 * Hn];     // 8 KB: 8 rows of h
    __shared__ float eps[Hn * 9];    // 9 KB: transpose buffer [k][row], pad 9
    __shared__ float red4[8];

    const int tid  = threadIdx.x;
    const int row0 = blockIdx.x * 8;

    for (int i = tid; i < 8 * Hn; i += 512)
        hs[i] = hsrc[row0 * Hn + i];
    __syncthreads();

    const int k  = tid & 255;
    const int g  = tid >> 8;           // 0 or 1: which 4-row group
    const int r0 = g * 4;

    float accT[4], accP[4];
    const float bhv = bh[k];
#pragma unroll
    for (int r = 0; r < 4; r++) { accT[r] = bhv; accP[r] = 0.0f; }

    const float* __restrict__ wtp = Wt + k;
    const float* __restrict__ wpp = Wp + k;

#pragma unroll 2
    for (int hh = 0; hh < Hn; hh += 4) {
        float wt[4], wp[4];
#pragma unroll
        for (int j = 0; j < 4; j++) {
            wt[j] = wtp[(hh + j) * Hn];
            wp[j] = wpp[(hh + j) * Hn];
        }
#pragma unroll
        for (int r = 0; r < 4; r++) {
            const float4 hv = *(const float4*)&hs[(r0 + r) * Hn + hh];
            accT[r] = fmaf(hv.x, wt[0], accT[r]);
            accT[r] = fmaf(hv.y, wt[1], accT[r]);
            accT[r] = fmaf(hv.z, wt[2], accT[r]);
            accT[r] = fmaf(hv.w, wt[3], accT[r]);
            accP[r] = fmaf(hv.x, wp[0], accP[r]);
            accP[r] = fmaf(hv.y, wp[1], accP[r]);
            accP[r] = fmaf(hv.z, wp[2], accP[r]);
            accP[r] = fmaf(hv.w, wp[3], accP[r]);
        }
    }

    const int row_base = row0 + r0;
#pragma unroll
    for (int r = 0; r < 4; r++)
        Egt[(row_base + r) * Hn + k] = __builtin_amdgcn_exp2f(accT[r] * CC);

    // Stage P-exponentials in LDS: eps[k][row], stride 9 (coprime 32).
#pragma unroll
    for (int r = 0; r < 4; r++)
        eps[k * 9 + r0 + r] = __builtin_amdgcn_exp2f(accP[r] * CC);
    __syncthreads();

    // Coalesced re-emit: thread t writes float4 for chunk c = t>>3, row = t&7.
    {
        const int b   = row0 >> 9;
        const int s0  = row0 & 511;
        const int c   = tid >> 3;       // 0..63: k-group
        const int row = tid & 7;
        float4 v;
        v.x = eps[(c * 4 + 0) * 9 + row];
        v.y = eps[(c * 4 + 1) * 9 + row];
        v.z = eps[(c * 4 + 2) * 9 + row];
        v.w = eps[(c * 4 + 3) * 9 + row];
        *(float4*)&Egp4[b * (Hn * Sn) + c * (4 * Sn) + (s0 + row) * 4] = v;
    }

    // --- W_a preprocessing (block 0 only; block-uniform branch) ---
    if (blockIdx.x == 0) {
        float w = (tid < 256) ? Wa[tid] : 0.0f;
#pragma unroll
        for (int off = 32; off >= 1; off >>= 1)
            w += __shfl_xor(w, off, 64);
        if ((tid & 63) == 0) red4[tid >> 6] = w;
        __syncthreads();
        if (tid < 256) wa2[tid] = -2.0f * Wa[tid];
        if (tid == 0) {
            float s = 0.0f;
            for (int i = 0; i < 8; i++) s += red4[i];
            cst[0] = -L2E * (s + ba[0]);
        }
    }
}

// ---------------------------------------------------------------------------
// Kernel B: scores. Pairwise-rcp factorized tanh:
//   wa/(1+xa) + wb/(1+xb) = (wa*db + wb*da) / (da*db)   [1 rcp per 2 elems]
// Two-deep float4 prefetch (~192cy issue->use) hides L2 latency.
// Grid = B * (S/4) = 512 blocks x 512 threads; thread = t' column.
// b = blockIdx&3 so each XCD (round-robin %8) touches one batch's tensors.
// ---------------------------------------------------------------------------
__global__ __launch_bounds__(512) void score_kernel(
    const float* __restrict__ Egt,  const float* __restrict__ Egp4,
    const float* __restrict__ wa2,  const float* __restrict__ cst,
    float* __restrict__ out_attn)
{
    __shared__ float red[4][8];

    const int tid = threadIdx.x;
    const int b   = blockIdx.x & 3;
    const int t0  = (blockIdx.x >> 2) << 2;

    const float* __restrict__ egt = Egt + (b * Sn + t0) * Hn;     // uniform
    const float4* __restrict__ ep = (const float4*)(Egp4 + b * (Hn * Sn));
    const int tp = tid;

    float acc[4] = {0.f, 0.f, 0.f, 0.f};

    float4 buf0 = ep[tp];            // k4 = 0
    float4 buf1 = ep[Sn + tp];       // k4 = 1
#pragma unroll 2
    for (int k4 = 0; k4 < 64; k4++) {
        const float4 nxt = (k4 < 62) ? ep[(k4 + 2) * Sn + tp] : buf1;
        const float* ca = (const float*)&buf0;
#pragma unroll
        for (int p = 0; p < 2; p++) {
            const float epa = ca[2 * p];
            const float epb = ca[2 * p + 1];
            const float w2a = wa2[k4 * 4 + 2 * p];       // s_load (uniform)
            const float w2b = wa2[k4 * 4 + 2 * p + 1];
#pragma unroll
            for (int r = 0; r < 4; r++) {
                const float ea = egt[r * Hn + k4 * 4 + 2 * p];      // s_load
                const float eb = egt[r * Hn + k4 * 4 + 2 * p + 1];
                const float da = fmaf(epa, ea, 1.0f);
                const float db = fmaf(epb, eb, 1.0f);
                const float den = da * db;
                const float num = fmaf(w2a, db, w2b * da);
                acc[r] = fmaf(num, __builtin_amdgcn_rcpf(den), acc[r]);
            }
        }
        buf0 = buf1;
        buf1 = nxt;
    }

    // score s = S_wa + acc + b_a ;  sig = 1/(1+e^{-s}) ; ex = e^{sig}
    const float k0 = cst[0];  // = -L2E*(S_wa + b_a)
    float ex[4];
#pragma unroll
    for (int r = 0; r < 4; r++) {
        const float e1  = __builtin_amdgcn_exp2f(fmaf(-L2E, acc[r], k0));
        const float sig = __builtin_amdgcn_rcpf(1.0f + e1);
        ex[r] = __builtin_amdgcn_exp2f(L2E * sig);  // sig in (0,1): no max-sub
    }

    // softmax denominator across 512 threads, per row r
    const int lane = tid & 63, wid = tid >> 6;
#pragma unroll
    for (int r = 0; r < 4; r++) {
        float v = ex[r];
#pragma unroll
        for (int off = 32; off >= 1; off >>= 1)
            v += __shfl_xor(v, off, 64);
        if (lane == 0) red[r][wid] = v;
    }
    __syncthreads();

#pragma unroll
    for (int r = 0; r < 4; r++) {
        const float tot = red[r][0] + red[r][1] + red[r][2] + red[r][3] +
                          red[r][4] + red[r][5] + red[r][6] + red[r][7];
        out_attn[(b * Sn + t0 + r) * Sn + tp] = ex[r] * __builtin_amdgcn_rcpf(tot);
    }
}

// ---------------------------------------------------------------------------
// Kernel C: out[b,t,:] = attn[b,t,:] @ h[b,:,:].
// attn rows block-uniform -> scalar s_loads; h streams as coalesced vector
// loads with a 2-deep prefetch pipeline. Same XCD swizzle as kernel B.
// Grid = 512 blocks x 512 threads; thread = (hcol, tp-half).
// ---------------------------------------------------------------------------
__global__ __launch_bounds__(512) void out_kernel(
    const float* __restrict__ hsrc, const float* __restrict__ attn,
    float* __restrict__ out)
{
    __shared__ float part[4][Hn];    // 4 KB

    const int tid  = threadIdx.x;
    const int b    = blockIdx.x & 3;
    const int t0   = (blockIdx.x >> 2) << 2;
    const int hcol = tid & 255;
    const int half = tid >> 8;
    // force wave-uniform tp base into an SGPR so attn loads scalarize
    const int tp0  = __builtin_amdgcn_readfirstlane(half << 8);

    const float* __restrict__ ar = attn + (b * Sn + t0) * Sn + tp0;
    const float* __restrict__ hb = hsrc + (b * Sn + tp0) * Hn + hcol;

    float a0 = 0.f, a1 = 0.f, a2 = 0.f, a3 = 0.f;

    float hv0[4], hv1[4];
#pragma unroll
    for (int i = 0; i < 4; i++) hv0[i] = hb[i * Hn];
#pragma unroll
    for (int i = 0; i < 4; i++) hv1[i] = hb[(4 + i) * Hn];

#pragma unroll 2
    for (int j = 0; j < 256; j += 4) {
        float hvn[4];
        const int jn = (j < 248) ? (j + 8) : j;
#pragma unroll
        for (int i = 0; i < 4; i++) hvn[i] = hb[(jn + i) * Hn];
#pragma unroll
        for (int i = 0; i < 4; i++) {
            a0 = fmaf(ar[0 * Sn + j + i], hv0[i], a0);   // s_load operands
            a1 = fmaf(ar[1 * Sn + j + i], hv0[i], a1);
            a2 = fmaf(ar[2 * Sn + j + i], hv0[i], a2);
            a3 = fmaf(ar[3 * Sn + j + i], hv0[i], a3);
        }
#pragma unroll
        for (int i = 0; i < 4; i++) { hv0[i] = hv1[i]; hv1[i] = hvn[i]; }
    }

    if (half == 1) {
        part[0][hcol] = a0; part[1][hcol] = a1;
        part[2][hcol] = a2; part[3][hcol] = a3;
    }
    __syncthreads();
    if (half == 0) {
        out[(b * Sn + t0 + 0) * Hn + hcol] = a0 + part[0][hcol];
        out[(b * Sn + t0 + 1) * Hn + hcol] = a1 + part[1][hcol];
        out[(b * Sn + t0 + 2) * Hn + hcol] = a2 + part[2][hcol];
        out[(b * Sn + t0 + 3) * Hn + hcol] = a3 + part[3][hcol];
    }
}

extern "C" void kernel_launch(void* const* d_in, const int* in_sizes, int n_in,
                              void* d_out, int out_size, void* d_ws, size_t ws_size,
                              hipStream_t stream) {
    const float* h   = (const float*)d_in[0];
    const float* Wt  = (const float*)d_in[1];
    const float* Wtp = (const float*)d_in[2];
    const float* bh  = (const float*)d_in[3];
    const float* Wa  = (const float*)d_in[4];
    const float* ba  = (const float*)d_in[5];

    float* out      = (float*)d_out;                 // (B,S,H) = 524288
    float* out_attn = out + Bn * Sn * Hn;            // (B,S,S) = 1048576

    float* ws   = (float*)d_ws;
    float* Egt  = ws;                                 // 524288 floats
    float* Egp4 = ws + Bn * Sn * Hn;                  // 524288 floats
    float* wa2  = ws + 2 * Bn * Sn * Hn;              // 256 floats
    float* cst  = wa2 + 256;                          // 1 float

    proj_kernel<<<dim3(2048 / 8), dim3(512), 0, stream>>>(
        h, Wt, Wtp, bh, Wa, ba, Egt, Egp4, wa2, cst);

    score_kernel<<<dim3(Bn * (Sn / 4)), dim3(512), 0, stream>>>(
        Egt, Egp4, wa2, cst, out_attn);

    out_kernel<<<dim3(Bn * (Sn / 4)), dim3(512), 0, stream>>>(
        h, out_attn, out);
}